// Round 6
// baseline (307.866 us; speedup 1.0000x reference)
//
#include <hip/hip_runtime.h>

#define N_NODES 50000
#define N_EDGES 800000
#define D_FEAT 32
#define NUM_GRAPHS 64
#define FEATS 320
#define NBIN 128                         // bins of 512 nodes (98 used)
#define BINSH 9
#define CE 4096                          // edges per binning chunk
#define NCHUNK ((N_EDGES + CE - 1) / CE) // 196
#define NPB ((N_NODES + 511) / 512)      // 98 place blocks

typedef unsigned short ushort4v __attribute__((ext_vector_type(4)));

// bf16 helpers (RNE pack, shift unpack) — values finite, no NaN path needed
__device__ __forceinline__ unsigned short f2bf(float f) {
    unsigned int u = __float_as_uint(f);
    u = (u + 0x7fffu + ((u >> 16) & 1u)) >> 16;
    return (unsigned short)u;
}
__device__ __forceinline__ float bf2f(unsigned short h) {
    return __uint_as_float((unsigned int)h << 16);
}
// bf16 pair unpack straight from a packed dword (1 VALU op each)
__device__ __forceinline__ float bflo(unsigned int u) { return __uint_as_float(u << 16); }
__device__ __forceinline__ float bfhi(unsigned int u) { return __uint_as_float(u & 0xffff0000u); }

// ---------------- atomic-free binning sort (counts -> positions -> place) ----

__global__ void binA_kernel(const int* __restrict__ dst, int* __restrict__ counts, int n) {
    __shared__ int h[NBIN];
    int t = threadIdx.x;
    if (t < NBIN) h[t] = 0;
    __syncthreads();
    int s0 = blockIdx.x * CE, e0 = min(s0 + CE, n);
    for (int i = s0 + t; i < e0; i += blockDim.x)
        atomicAdd(&h[dst[i] >> BINSH], 1);
    __syncthreads();
    if (t < NBIN) counts[blockIdx.x * NBIN + t] = h[t];
}

__global__ void binB_kernel(int* __restrict__ counts, int* __restrict__ binBase) {
    __shared__ int s[NBIN];
    int b = threadIdx.x;
    int tot = 0;
    #pragma unroll 8
    for (int c = 0; c < NCHUNK; ++c) tot += counts[c * NBIN + b];
    s[b] = tot;
    __syncthreads();
    for (int off = 1; off < NBIN; off <<= 1) {
        int u = (b >= off) ? s[b - off] : 0;
        __syncthreads();
        s[b] += u;
        __syncthreads();
    }
    int base = s[b] - tot;   // exclusive
    binBase[b] = base;
    if (b == NBIN - 1) binBase[NBIN] = s[b];
    int running = base;
    #pragma unroll 4
    for (int c = 0; c < NCHUNK; ++c) {
        int idx = c * NBIN + b;
        int v = counts[idx];
        counts[idx] = running;
        running += v;
    }
}

__global__ __launch_bounds__(256) void binC_kernel(const int* __restrict__ src,
                                                   const int* __restrict__ dst,
                                                   const float* __restrict__ w,
                                                   const int* __restrict__ counts,
                                                   int2* __restrict__ tmp, int n) {
    __shared__ int h[NBIN], sc[NBIN], cur[NBIN], gbase[NBIN];
    __shared__ int2 srec[CE];
    __shared__ unsigned char sbin[CE];
    int t = threadIdx.x;
    if (t < NBIN) h[t] = 0;
    __syncthreads();
    int s0 = blockIdx.x * CE, e0 = min(s0 + CE, n);
    int cnt = e0 - s0;
    for (int i = s0 + t; i < e0; i += blockDim.x)
        atomicAdd(&h[dst[i] >> BINSH], 1);
    __syncthreads();
    if (t < NBIN) sc[t] = h[t];
    __syncthreads();
    for (int off = 1; off < NBIN; off <<= 1) {
        int u = (t < NBIN && t >= off) ? sc[t - off] : 0;
        __syncthreads();
        if (t < NBIN) sc[t] += u;   // inclusive; exclusive = sc[b]-h[b]
        __syncthreads();
    }
    if (t < NBIN) {
        cur[t] = 0;
        gbase[t] = counts[blockIdx.x * NBIN + t];
    }
    __syncthreads();
    for (int i = s0 + t; i < e0; i += blockDim.x) {
        int d = dst[i];
        int b = d >> BINSH;
        int pos = (sc[b] - h[b]) + atomicAdd(&cur[b], 1);   // LDS atomic: cheap
        srec[pos] = make_int2(src[i] | ((int)f2bf(w[i]) << 16), d & 511);
        sbin[pos] = (unsigned char)b;
    }
    __syncthreads();
    for (int j = t; j < cnt; j += blockDim.x) {
        int b = sbin[j];
        tmp[gbase[b] + (j - (sc[b] - h[b]))] = srec[j];   // coalesced runs per bin
    }
}

__global__ __launch_bounds__(256) void place_kernel(const int* __restrict__ binBase,
                                                    const int2* __restrict__ tmp,
                                                    unsigned int* __restrict__ edges,
                                                    int* __restrict__ rowptr, int n) {
    __shared__ int h[512], sc[512], cur[512];
    int b = blockIdx.x;
    int t = threadIdx.x;
    int base = binBase[b], end = binBase[b + 1];
    for (int i = t; i < 512; i += 256) { h[i] = 0; cur[i] = 0; }
    __syncthreads();
    for (int e = base + t; e < end; e += 256)
        atomicAdd(&h[tmp[e].y], 1);
    __syncthreads();
    for (int i = t; i < 512; i += 256) sc[i] = h[i];
    __syncthreads();
    for (int off = 1; off < 512; off <<= 1) {
        int i0 = t, i1 = t + 256;
        int a0 = (i0 >= off) ? sc[i0 - off] : 0;
        int a1 = (i1 >= off) ? sc[i1 - off] : 0;
        __syncthreads();
        sc[i0] += a0;
        sc[i1] += a1;
        __syncthreads();
    }
    int node0 = b << BINSH;
    for (int i = t; i < 512; i += 256) {
        int node = node0 + i;
        if (node <= n) rowptr[node] = base + sc[i] - h[i];   // exclusive
    }
    if (b == 0 && t == 0) rowptr[0] = 0;
    __syncthreads();
    for (int e = base + t; e < end; e += 256) {
        int2 p = tmp[e];
        int loc = p.y;
        int pos = base + (sc[loc] - h[loc]) + atomicAdd(&cur[loc], 1);
        edges[pos] = (unsigned int)p.x;
    }
}

// ---------------- prep: X -> bf16 conversion + graph boundaries -------------

__global__ void prep_kernel(const float4* __restrict__ xin, ushort4* __restrict__ xout,
                            const int* __restrict__ batch, int* __restrict__ gstart, int n) {
    int i = blockIdx.x * blockDim.x + threadIdx.x;
    if (i < n * 8) {
        float4 v = xin[i];
        ushort4 o;
        o.x = f2bf(v.x); o.y = f2bf(v.y); o.z = f2bf(v.z); o.w = f2bf(v.w);
        xout[i] = o;
    }
    if (i < n) {
        int g = batch[i];
        int gp = (i == 0) ? -1 : batch[i - 1];
        for (int gg = gp + 1; gg <= g; ++gg) gstart[gg] = i;
        if (i == n - 1)
            for (int gg = g + 1; gg <= NUM_GRAPHS; ++gg) gstart[gg] = n;
    }
}

// ---------------- SpMM (pull, no atomics), D=32 bf16, 4B edge recs ----------
// Experiment ledger (r0-r5): int8 half-footprint = null; 4-lane/16-unroll MLP
// = null; LDS record staging = -2%. All configs oversubscribe the memory
// system (waves x in-flight segments ~400-800k >> system capacity), which
// backpressures and serves random 64B gathers at ~16.7 lines/cy chip-wide
// (~2.1/cy/XCD) => 12 x 800k lines ~ 230us. This is the LLC/fabric random-
// request service wall (x is LLC-resident, L2 cold-invalidated per dispatch;
// predecessor's XCD warm/copy/split attempts failed 3x).
// This round: best-known config (direct nt record loads) + tail smoothing:
// 128-thread blocks, 8 lanes/node -> 3125 blocks (12.2/CU, +8% tail vs +33%
// at 782 blocks), 24 waves/CU, 16-deep unroll.

__global__ __launch_bounds__(128, 4) void spmm_kernel(const ushort4* __restrict__ xin,
                                                      ushort4* __restrict__ yout,
                                                      const int* __restrict__ rowptr,
                                                      const unsigned int* __restrict__ edges,
                                                      int n) {
    int lane = threadIdx.x & 7;
    int node = (blockIdx.x * blockDim.x + threadIdx.x) >> 3;
    if (node >= n) return;
    int e0 = rowptr[node], e1 = rowptr[node + 1];
    float a0 = 0.f, a1 = 0.f, a2 = 0.f, a3 = 0.f;
    int e = e0;
    int e16 = e0 + ((e1 - e0) & ~15);
    for (; e < e16; e += 16) {
        unsigned int r[16];
        #pragma unroll
        for (int u = 0; u < 16; ++u) r[u] = __builtin_nontemporal_load(&edges[e + u]);
        ushort4 v[16];
        #pragma unroll
        for (int u = 0; u < 16; ++u)
            v[u] = xin[(size_t)(r[u] & 0xffffu) * 8 + lane];
        #pragma unroll
        for (int u = 0; u < 16; ++u) {
            float w = bfhi(r[u]);
            a0 += bf2f(v[u].x) * w;
            a1 += bf2f(v[u].y) * w;
            a2 += bf2f(v[u].z) * w;
            a3 += bf2f(v[u].w) * w;
        }
    }
    int e4 = e0 + ((e1 - e0) & ~3);
    for (; e < e4; e += 4) {
        unsigned int r[4];
        #pragma unroll
        for (int u = 0; u < 4; ++u) r[u] = __builtin_nontemporal_load(&edges[e + u]);
        ushort4 v[4];
        #pragma unroll
        for (int u = 0; u < 4; ++u)
            v[u] = xin[(size_t)(r[u] & 0xffffu) * 8 + lane];
        #pragma unroll
        for (int u = 0; u < 4; ++u) {
            float w = bfhi(r[u]);
            a0 += bf2f(v[u].x) * w;
            a1 += bf2f(v[u].y) * w;
            a2 += bf2f(v[u].z) * w;
            a3 += bf2f(v[u].w) * w;
        }
    }
    for (; e < e1; ++e) {
        unsigned int r = __builtin_nontemporal_load(&edges[e]);
        ushort4 v = xin[(size_t)(r & 0xffffu) * 8 + lane];
        float w = bfhi(r);
        a0 += bf2f(v.x) * w; a1 += bf2f(v.y) * w;
        a2 += bf2f(v.z) * w; a3 += bf2f(v.w) * w;
    }
    ushort4v o;
    o.x = f2bf(a0); o.y = f2bf(a1); o.z = f2bf(a2); o.w = f2bf(a3);
    __builtin_nontemporal_store(o, (ushort4v*)&yout[(size_t)node * 8 + lane]);
}

// ---------------- fused pooling: one pass, 10 distinct arrays loaded once ----
// All 10 terms derive from 10 distinct chain arrays {y1..y6,y8,y9,y10,y12}:
// load each node-row once (32MB total), compute all 10 terms, block-reduce in
// LDS, 320 atomics/block.

struct PoolPtrs { const unsigned short* a[10]; }; // y1,y2,y3,y4,y5,y6,y8,y9,y10,y12

__global__ __launch_bounds__(256) void pool_kernel(PoolPtrs P, const int* __restrict__ gstart,
                                                   float* __restrict__ out) {
    __shared__ float red[8][FEATS];
    int t = threadIdx.x;
    int f = t & 31;
    int sub = t >> 5;                 // 0..7
    int g = blockIdx.x >> 4;
    int s = blockIdx.x & 15;
    int gs = gstart[g], ge = gstart[g + 1];
    int len = ge - gs;
    int i0 = gs + ((len * s) >> 4);
    int i1 = gs + ((len * (s + 1)) >> 4);
    float acc[10];
    #pragma unroll
    for (int k = 0; k < 10; ++k) acc[k] = 0.f;
    for (int i = i0 + sub; i < i1; i += 8) {
        float v[10];
        #pragma unroll
        for (int k = 0; k < 10; ++k) v[k] = bf2f(P.a[k][(size_t)i * 32 + f]);
        acc[0] += v[6];                  // F0: y8
        acc[1] += fabsf(v[0] - v[1]);    // |y1-y2|
        acc[2] += fabsf(v[1] - v[3]);    // |y2-y4|
        acc[3] += fabsf(v[3] - v[6]);    // |y4-y8|
        acc[4] += fabsf(v[2] - v[1]);    // |y3-y2|
        acc[5] += fabsf(v[4] - v[2]);    // |y5-y3|
        acc[6] += fabsf(v[7] - v[4]);    // |y9-y5|
        acc[7] += fabsf(v[5] - v[3]);    // |y6-y4|
        acc[8] += fabsf(v[8] - v[5]);    // |y10-y6|
        acc[9] += fabsf(v[9] - v[6]);    // |y12-y8|
    }
    #pragma unroll
    for (int k = 0; k < 10; ++k) red[sub][k * 32 + f] = acc[k];
    __syncthreads();
    float invl = 1.0f / (float)max(len, 1);
    for (int o = t; o < FEATS; o += 256) {
        float ssum = 0.f;
        #pragma unroll
        for (int j = 0; j < 8; ++j) ssum += red[j][o];
        atomicAdd(&out[g * FEATS + o], ssum * invl);
    }
}

// ---------------- host launch ----------------

extern "C" void kernel_launch(void* const* d_in, const int* in_sizes, int n_in,
                              void* d_out, int out_size, void* d_ws, size_t ws_size,
                              hipStream_t stream) {
    const float* X     = (const float*)d_in[0];
    const int*   ei    = (const int*)d_in[1];
    const float* ew    = (const float*)d_in[2];
    const int*   batch = (const int*)d_in[3];
    float* out = (float*)d_out;

    const int N = N_NODES, E = N_EDGES;
    const int* src = ei;
    const int* dst = ei + E;

    char* base = (char*)d_ws;
    size_t off = 0;
    auto alloc = [&](size_t bytes) -> void* {
        void* p = base + off;
        off += (bytes + 255) & ~(size_t)255;
        return p;
    };
    // bf16 diffusion chain buffers y[k] = P^k X, k=0..12 (y[0] = bf16(X))
    unsigned short* y[13];
    for (int k = 0; k <= 12; ++k) y[k] = (unsigned short*)alloc((size_t)N * 32 * 2);

    int*  rowptr  = (int*)alloc((size_t)(N + 4) * 4);
    int*  gstart  = (int*)alloc((NUM_GRAPHS + 1) * 4);
    int*  counts  = (int*)alloc((size_t)NCHUNK * NBIN * 4);
    int*  binBase = (int*)alloc((NBIN + 1) * 4);
    int2* tmp     = (int2*)alloc((size_t)E * 8);
    unsigned int* edges = (unsigned int*)alloc((size_t)E * 4);

    hipMemsetAsync(out, 0, (size_t)out_size * 4, stream);

    // atomic-free CSR build: counts -> positions -> grouped tmp -> edges+rowptr
    binA_kernel<<<NCHUNK, 256, 0, stream>>>(dst, counts, E);
    binB_kernel<<<1, NBIN, 0, stream>>>(counts, binBase);
    binC_kernel<<<NCHUNK, 256, 0, stream>>>(src, dst, ew, counts, tmp, E);
    place_kernel<<<NPB, 256, 0, stream>>>(binBase, tmp, edges, rowptr, N);

    // X -> bf16 + graph boundaries (merged)
    prep_kernel<<<(N * 8 + 255) / 256, 256, 0, stream>>>((const float4*)X, (ushort4*)y[0],
                                                         batch, gstart, N);

    // ---- single D=32 bf16 diffusion chain: y[k] = P y[k-1], k = 1..12
    const int SPMM_GRID = (N * 8 + 127) / 128;  // 3125 blocks, 16 nodes/block
    for (int k = 1; k <= 12; ++k) {
        spmm_kernel<<<SPMM_GRID, 128, 0, stream>>>((const ushort4*)y[k - 1], (ushort4*)y[k],
                                                   rowptr, edges, N);
    }

    // ---- fused single-pass pooling (mean included) of all 10 terms
    // F0 = y8 | F1: |y1-y2|, |y2-y4|, |y4-y8|
    // F2 (ref order): |y3-y2|, |y5-y3|, |y9-y5|, |y6-y4|, |y10-y6|, |y12-y8|
    {
        PoolPtrs p;
        const int idx[10] = {1, 2, 3, 4, 5, 6, 8, 9, 10, 12};
        for (int k = 0; k < 10; ++k) p.a[k] = y[idx[k]];
        pool_kernel<<<NUM_GRAPHS * 16, 256, 0, stream>>>(p, gstart, out);
    }
}

// Round 7
// 267.026 us; speedup vs baseline: 1.1529x; 1.1529x over previous
//
#include <hip/hip_runtime.h>

#define N_NODES 50000
#define N_EDGES 800000
#define D_FEAT 32
#define NUM_GRAPHS 64
#define FEATS 320
#define NBIN 128                         // bins of 512 nodes (98 used)
#define BINSH 9
#define CE 4096                          // edges per binning chunk
#define NCHUNK ((N_EDGES + CE - 1) / CE) // 196
#define NPB ((N_NODES + 511) / 512)      // 98 place blocks

// bf16 helpers (RNE pack, shift unpack) — values finite, no NaN path needed
__device__ __forceinline__ unsigned short f2bf(float f) {
    unsigned int u = __float_as_uint(f);
    u = (u + 0x7fffu + ((u >> 16) & 1u)) >> 16;
    return (unsigned short)u;
}
__device__ __forceinline__ float bf2f(unsigned short h) {
    return __uint_as_float((unsigned int)h << 16);
}
// bf16 pair unpack straight from a packed dword (1 VALU op each)
__device__ __forceinline__ float bflo(unsigned int u) { return __uint_as_float(u << 16); }
__device__ __forceinline__ float bfhi(unsigned int u) { return __uint_as_float(u & 0xffff0000u); }

// ---------------- atomic-free binning sort (counts -> positions -> place) ----

__global__ void binA_kernel(const int* __restrict__ dst, int* __restrict__ counts, int n) {
    __shared__ int h[NBIN];
    int t = threadIdx.x;
    if (t < NBIN) h[t] = 0;
    __syncthreads();
    int s0 = blockIdx.x * CE, e0 = min(s0 + CE, n);
    for (int i = s0 + t; i < e0; i += blockDim.x)
        atomicAdd(&h[dst[i] >> BINSH], 1);
    __syncthreads();
    if (t < NBIN) counts[blockIdx.x * NBIN + t] = h[t];
}

__global__ void binB_kernel(int* __restrict__ counts, int* __restrict__ binBase) {
    __shared__ int s[NBIN];
    int b = threadIdx.x;
    int tot = 0;
    #pragma unroll 8
    for (int c = 0; c < NCHUNK; ++c) tot += counts[c * NBIN + b];
    s[b] = tot;
    __syncthreads();
    for (int off = 1; off < NBIN; off <<= 1) {
        int u = (b >= off) ? s[b - off] : 0;
        __syncthreads();
        s[b] += u;
        __syncthreads();
    }
    int base = s[b] - tot;   // exclusive
    binBase[b] = base;
    if (b == NBIN - 1) binBase[NBIN] = s[b];
    int running = base;
    #pragma unroll 4
    for (int c = 0; c < NCHUNK; ++c) {
        int idx = c * NBIN + b;
        int v = counts[idx];
        counts[idx] = running;
        running += v;
    }
}

__global__ __launch_bounds__(256) void binC_kernel(const int* __restrict__ src,
                                                   const int* __restrict__ dst,
                                                   const float* __restrict__ w,
                                                   const int* __restrict__ counts,
                                                   int2* __restrict__ tmp, int n) {
    __shared__ int h[NBIN], sc[NBIN], cur[NBIN], gbase[NBIN];
    __shared__ int2 srec[CE];
    __shared__ unsigned char sbin[CE];
    int t = threadIdx.x;
    if (t < NBIN) h[t] = 0;
    __syncthreads();
    int s0 = blockIdx.x * CE, e0 = min(s0 + CE, n);
    int cnt = e0 - s0;
    for (int i = s0 + t; i < e0; i += blockDim.x)
        atomicAdd(&h[dst[i] >> BINSH], 1);
    __syncthreads();
    if (t < NBIN) sc[t] = h[t];
    __syncthreads();
    for (int off = 1; off < NBIN; off <<= 1) {
        int u = (t < NBIN && t >= off) ? sc[t - off] : 0;
        __syncthreads();
        if (t < NBIN) sc[t] += u;   // inclusive; exclusive = sc[b]-h[b]
        __syncthreads();
    }
    if (t < NBIN) {
        cur[t] = 0;
        gbase[t] = counts[blockIdx.x * NBIN + t];
    }
    __syncthreads();
    for (int i = s0 + t; i < e0; i += blockDim.x) {
        int d = dst[i];
        int b = d >> BINSH;
        int pos = (sc[b] - h[b]) + atomicAdd(&cur[b], 1);   // LDS atomic: cheap
        srec[pos] = make_int2(src[i] | ((int)f2bf(w[i]) << 16), d & 511);
        sbin[pos] = (unsigned char)b;
    }
    __syncthreads();
    for (int j = t; j < cnt; j += blockDim.x) {
        int b = sbin[j];
        tmp[gbase[b] + (j - (sc[b] - h[b]))] = srec[j];   // coalesced runs per bin
    }
}

__global__ __launch_bounds__(256) void place_kernel(const int* __restrict__ binBase,
                                                    const int2* __restrict__ tmp,
                                                    unsigned int* __restrict__ edges,
                                                    int* __restrict__ rowptr, int n) {
    __shared__ int h[512], sc[512], cur[512];
    int b = blockIdx.x;
    int t = threadIdx.x;
    int base = binBase[b], end = binBase[b + 1];
    for (int i = t; i < 512; i += 256) { h[i] = 0; cur[i] = 0; }
    __syncthreads();
    for (int e = base + t; e < end; e += 256)
        atomicAdd(&h[tmp[e].y], 1);
    __syncthreads();
    for (int i = t; i < 512; i += 256) sc[i] = h[i];
    __syncthreads();
    for (int off = 1; off < 512; off <<= 1) {
        int i0 = t, i1 = t + 256;
        int a0 = (i0 >= off) ? sc[i0 - off] : 0;
        int a1 = (i1 >= off) ? sc[i1 - off] : 0;
        __syncthreads();
        sc[i0] += a0;
        sc[i1] += a1;
        __syncthreads();
    }
    int node0 = b << BINSH;
    for (int i = t; i < 512; i += 256) {
        int node = node0 + i;
        if (node <= n) rowptr[node] = base + sc[i] - h[i];   // exclusive
    }
    if (b == 0 && t == 0) rowptr[0] = 0;
    __syncthreads();
    for (int e = base + t; e < end; e += 256) {
        int2 p = tmp[e];
        int loc = p.y;
        int pos = base + (sc[loc] - h[loc]) + atomicAdd(&cur[loc], 1);
        edges[pos] = (unsigned int)p.x;
    }
}

// ---------------- prep: X -> bf16 conversion + graph boundaries -------------

__global__ void prep_kernel(const float4* __restrict__ xin, ushort4* __restrict__ xout,
                            const int* __restrict__ batch, int* __restrict__ gstart, int n) {
    int i = blockIdx.x * blockDim.x + threadIdx.x;
    if (i < n * 8) {
        float4 v = xin[i];
        ushort4 o;
        o.x = f2bf(v.x); o.y = f2bf(v.y); o.z = f2bf(v.z); o.w = f2bf(v.w);
        xout[i] = o;
    }
    if (i < n) {
        int g = batch[i];
        int gp = (i == 0) ? -1 : batch[i - 1];
        for (int gg = gp + 1; gg <= g; ++gg) gstart[gg] = i;
        if (i == n - 1)
            for (int gg = g + 1; gg <= NUM_GRAPHS; ++gg) gstart[gg] = n;
    }
}

// ---------------- SpMM (pull, no atomics), D=32 bf16, 4B edge recs ----------
// FINAL config = best measured (r2: 267.9us). Falsified-lever ledger for the
// ~19us/step wall (do NOT retry): int8 half-footprint (r0 null), 2x MLP via
// 4-lane/16-unroll (r1 ~null), LDS record dedup (r5 -2%), nt hints (r5/r6
// NEGATIVE - nt y-stores evict lines the next step re-reads), 8-lane/128thr
// shape (r6 -15%), XCD copy/warm/split (predecessor, 3x failed).
// Structural wall: each SpMM dispatch re-pulls the full 3.2MB feature array
// into every XCD's L2 (cross-XCD-written y forces turnover at each dispatch
// boundary); 12 serial sweeps x ~19us + ~28us CSR/prep/pool = ~267us total.
// Invariant to footprint, request count, MLP, staging, hints, and shape.

__global__ __launch_bounds__(256, 4) void spmm_kernel(const uint4* __restrict__ xin,
                                                      uint4* __restrict__ yout,
                                                      const int* __restrict__ rowptr,
                                                      const unsigned int* __restrict__ edges,
                                                      int n) {
    int lane = threadIdx.x & 3;
    int node = (blockIdx.x * blockDim.x + threadIdx.x) >> 2;
    if (node >= n) return;
    int e0 = rowptr[node], e1 = rowptr[node + 1];
    float a0 = 0.f, a1 = 0.f, a2 = 0.f, a3 = 0.f;
    float a4 = 0.f, a5 = 0.f, a6 = 0.f, a7 = 0.f;
    int e = e0;
    int e16 = e0 + ((e1 - e0) & ~15);
    for (; e < e16; e += 16) {
        unsigned int r[16];
        #pragma unroll
        for (int u = 0; u < 16; ++u) r[u] = edges[e + u];
        uint4 v[16];
        #pragma unroll
        for (int u = 0; u < 16; ++u)
            v[u] = xin[(size_t)(r[u] & 0xffffu) * 4 + lane];
        #pragma unroll
        for (int u = 0; u < 16; ++u) {
            float w = bfhi(r[u]);
            a0 += bflo(v[u].x) * w; a1 += bfhi(v[u].x) * w;
            a2 += bflo(v[u].y) * w; a3 += bfhi(v[u].y) * w;
            a4 += bflo(v[u].z) * w; a5 += bfhi(v[u].z) * w;
            a6 += bflo(v[u].w) * w; a7 += bfhi(v[u].w) * w;
        }
    }
    int e4 = e0 + ((e1 - e0) & ~3);
    for (; e < e4; e += 4) {
        unsigned int r[4];
        #pragma unroll
        for (int u = 0; u < 4; ++u) r[u] = edges[e + u];
        uint4 v[4];
        #pragma unroll
        for (int u = 0; u < 4; ++u)
            v[u] = xin[(size_t)(r[u] & 0xffffu) * 4 + lane];
        #pragma unroll
        for (int u = 0; u < 4; ++u) {
            float w = bfhi(r[u]);
            a0 += bflo(v[u].x) * w; a1 += bfhi(v[u].x) * w;
            a2 += bflo(v[u].y) * w; a3 += bfhi(v[u].y) * w;
            a4 += bflo(v[u].z) * w; a5 += bfhi(v[u].z) * w;
            a6 += bflo(v[u].w) * w; a7 += bfhi(v[u].w) * w;
        }
    }
    for (; e < e1; ++e) {
        unsigned int r = edges[e];
        uint4 v = xin[(size_t)(r & 0xffffu) * 4 + lane];
        float w = bfhi(r);
        a0 += bflo(v.x) * w; a1 += bfhi(v.x) * w;
        a2 += bflo(v.y) * w; a3 += bfhi(v.y) * w;
        a4 += bflo(v.z) * w; a5 += bfhi(v.z) * w;
        a6 += bflo(v.w) * w; a7 += bfhi(v.w) * w;
    }
    uint4 o;
    o.x = (unsigned int)f2bf(a0) | ((unsigned int)f2bf(a1) << 16);
    o.y = (unsigned int)f2bf(a2) | ((unsigned int)f2bf(a3) << 16);
    o.z = (unsigned int)f2bf(a4) | ((unsigned int)f2bf(a5) << 16);
    o.w = (unsigned int)f2bf(a6) | ((unsigned int)f2bf(a7) << 16);
    yout[(size_t)node * 4 + lane] = o;
}

// ---------------- fused pooling: one pass, 10 distinct arrays loaded once ----
// All 10 terms derive from 10 distinct chain arrays {y1..y6,y8,y9,y10,y12}:
// load each node-row once (32MB total), compute all 10 terms, block-reduce in
// LDS, 320 atomics/block.

struct PoolPtrs { const unsigned short* a[10]; }; // y1,y2,y3,y4,y5,y6,y8,y9,y10,y12

__global__ __launch_bounds__(256) void pool_kernel(PoolPtrs P, const int* __restrict__ gstart,
                                                   float* __restrict__ out) {
    __shared__ float red[8][FEATS];
    int t = threadIdx.x;
    int f = t & 31;
    int sub = t >> 5;                 // 0..7
    int g = blockIdx.x >> 4;
    int s = blockIdx.x & 15;
    int gs = gstart[g], ge = gstart[g + 1];
    int len = ge - gs;
    int i0 = gs + ((len * s) >> 4);
    int i1 = gs + ((len * (s + 1)) >> 4);
    float acc[10];
    #pragma unroll
    for (int k = 0; k < 10; ++k) acc[k] = 0.f;
    for (int i = i0 + sub; i < i1; i += 8) {
        float v[10];
        #pragma unroll
        for (int k = 0; k < 10; ++k) v[k] = bf2f(P.a[k][(size_t)i * 32 + f]);
        acc[0] += v[6];                  // F0: y8
        acc[1] += fabsf(v[0] - v[1]);    // |y1-y2|
        acc[2] += fabsf(v[1] - v[3]);    // |y2-y4|
        acc[3] += fabsf(v[3] - v[6]);    // |y4-y8|
        acc[4] += fabsf(v[2] - v[1]);    // |y3-y2|
        acc[5] += fabsf(v[4] - v[2]);    // |y5-y3|
        acc[6] += fabsf(v[7] - v[4]);    // |y9-y5|
        acc[7] += fabsf(v[5] - v[3]);    // |y6-y4|
        acc[8] += fabsf(v[8] - v[5]);    // |y10-y6|
        acc[9] += fabsf(v[9] - v[6]);    // |y12-y8|
    }
    #pragma unroll
    for (int k = 0; k < 10; ++k) red[sub][k * 32 + f] = acc[k];
    __syncthreads();
    float invl = 1.0f / (float)max(len, 1);
    for (int o = t; o < FEATS; o += 256) {
        float ssum = 0.f;
        #pragma unroll
        for (int j = 0; j < 8; ++j) ssum += red[j][o];
        atomicAdd(&out[g * FEATS + o], ssum * invl);
    }
}

// ---------------- host launch ----------------

extern "C" void kernel_launch(void* const* d_in, const int* in_sizes, int n_in,
                              void* d_out, int out_size, void* d_ws, size_t ws_size,
                              hipStream_t stream) {
    const float* X     = (const float*)d_in[0];
    const int*   ei    = (const int*)d_in[1];
    const float* ew    = (const float*)d_in[2];
    const int*   batch = (const int*)d_in[3];
    float* out = (float*)d_out;

    const int N = N_NODES, E = N_EDGES;
    const int* src = ei;
    const int* dst = ei + E;

    char* base = (char*)d_ws;
    size_t off = 0;
    auto alloc = [&](size_t bytes) -> void* {
        void* p = base + off;
        off += (bytes + 255) & ~(size_t)255;
        return p;
    };
    // bf16 diffusion chain buffers y[k] = P^k X, k=0..12 (y[0] = bf16(X))
    unsigned short* y[13];
    for (int k = 0; k <= 12; ++k) y[k] = (unsigned short*)alloc((size_t)N * 32 * 2);

    int*  rowptr  = (int*)alloc((size_t)(N + 4) * 4);
    int*  gstart  = (int*)alloc((NUM_GRAPHS + 1) * 4);
    int*  counts  = (int*)alloc((size_t)NCHUNK * NBIN * 4);
    int*  binBase = (int*)alloc((NBIN + 1) * 4);
    int2* tmp     = (int2*)alloc((size_t)E * 8);
    unsigned int* edges = (unsigned int*)alloc((size_t)E * 4);

    hipMemsetAsync(out, 0, (size_t)out_size * 4, stream);

    // atomic-free CSR build: counts -> positions -> grouped tmp -> edges+rowptr
    binA_kernel<<<NCHUNK, 256, 0, stream>>>(dst, counts, E);
    binB_kernel<<<1, NBIN, 0, stream>>>(counts, binBase);
    binC_kernel<<<NCHUNK, 256, 0, stream>>>(src, dst, ew, counts, tmp, E);
    place_kernel<<<NPB, 256, 0, stream>>>(binBase, tmp, edges, rowptr, N);

    // X -> bf16 + graph boundaries (merged)
    prep_kernel<<<(N * 8 + 255) / 256, 256, 0, stream>>>((const float4*)X, (ushort4*)y[0],
                                                         batch, gstart, N);

    // ---- single D=32 bf16 diffusion chain: y[k] = P y[k-1], k = 1..12
    const int SPMM_GRID = (N * 4 + 255) / 256;  // 782 blocks, 64 nodes/block
    for (int k = 1; k <= 12; ++k) {
        spmm_kernel<<<SPMM_GRID, 256, 0, stream>>>((const uint4*)y[k - 1], (uint4*)y[k],
                                                   rowptr, edges, N);
    }

    // ---- fused single-pass pooling (mean included) of all 10 terms
    // F0 = y8 | F1: |y1-y2|, |y2-y4|, |y4-y8|
    // F2 (ref order): |y3-y2|, |y5-y3|, |y9-y5|, |y6-y4|, |y10-y6|, |y12-y8|
    {
        PoolPtrs p;
        const int idx[10] = {1, 2, 3, 4, 5, 6, 8, 9, 10, 12};
        for (int k = 0; k < 10; ++k) p.a[k] = y[idx[k]];
        pool_kernel<<<NUM_GRAPHS * 16, 256, 0, stream>>>(p, gstart, out);
    }
}